// Round 2
// baseline (1234.317 us; speedup 1.0000x reference)
//
#include <hip/hip_runtime.h>
#include <math.h>

#define ZDIM   512
#define MDIM   512
#define HHN    511
#define NBATCH 65536

// ---------------------------------------------------------------------------
// K1: normalize v rows -> vn ; rrii[m] = Rs[m,m] * r2diag[m]
// ---------------------------------------------------------------------------
__global__ void __launch_bounds__(64) prep_kernel(const float* __restrict__ v,
                                                  const float* __restrict__ Rs,
                                                  const float* __restrict__ r2diag,
                                                  float* __restrict__ vn,
                                                  float* __restrict__ rrii) {
    int b    = blockIdx.x;
    int lane = threadIdx.x;  // 64
    if (b < HHN) {
        const float4* src = reinterpret_cast<const float4*>(v + (size_t)b * ZDIM);
        float4 a0 = src[lane * 2];
        float4 a1 = src[lane * 2 + 1];
        float s = a0.x*a0.x + a0.y*a0.y + a0.z*a0.z + a0.w*a0.w
                + a1.x*a1.x + a1.y*a1.y + a1.z*a1.z + a1.w*a1.w;
#pragma unroll
        for (int off = 32; off >= 1; off >>= 1) s += __shfl_xor(s, off, 64);
        float inv = 1.0f / sqrtf(s);
        float4 o0 = make_float4(a0.x*inv, a0.y*inv, a0.z*inv, a0.w*inv);
        float4 o1 = make_float4(a1.x*inv, a1.y*inv, a1.z*inv, a1.w*inv);
        float4* dst = reinterpret_cast<float4*>(vn + (size_t)b * ZDIM);
        dst[lane * 2]     = o0;
        dst[lane * 2 + 1] = o1;
    } else {
        for (int m = lane; m < MDIM; m += 64)
            rrii[m] = Rs[(size_t)m * MDIM + m] * r2diag[m];
    }
}

// ---------------------------------------------------------------------------
// K2: Householder product, row-parallel. One wave per row of Q.
// Row r of Q starts as e_r and evolves independently:
//   q_r <- q_r - 2 (q_r . v_i) v_i   for i = 0..510 (reference scan order)
// Row held in 8 VGPRs/lane (col = lane*8 + j). vn row prefetched from L2.
// ---------------------------------------------------------------------------
__global__ void __launch_bounds__(256) householder_kernel(const float* __restrict__ vn,
                                                          float* __restrict__ Q) {
    int wave = threadIdx.x >> 6;          // 0..3
    int lane = threadIdx.x & 63;
    int r    = blockIdx.x * 4 + wave;     // 0..511

    float q[8];
#pragma unroll
    for (int j = 0; j < 8; ++j) q[j] = 0.0f;
    int base = r - lane * 8;
    if (base >= 0 && base < 8) q[base] = 1.0f;

    const float4* vn4 = reinterpret_cast<const float4*>(vn);
    float4 va = vn4[lane * 2];
    float4 vb = vn4[lane * 2 + 1];
    for (int i = 0; i < HHN; ++i) {
        float4 ca = va, cb = vb;
        if (i + 1 < HHN) {                      // prefetch next reflector
            va = vn4[(size_t)(i + 1) * (ZDIM / 4) + lane * 2];
            vb = vn4[(size_t)(i + 1) * (ZDIM / 4) + lane * 2 + 1];
        }
        float d = q[0]*ca.x + q[1]*ca.y + q[2]*ca.z + q[3]*ca.w
                + q[4]*cb.x + q[5]*cb.y + q[6]*cb.z + q[7]*cb.w;
#pragma unroll
        for (int off = 32; off >= 1; off >>= 1) d += __shfl_xor(d, off, 64);
        float s = -2.0f * d;
        q[0] = fmaf(s, ca.x, q[0]); q[1] = fmaf(s, ca.y, q[1]);
        q[2] = fmaf(s, ca.z, q[2]); q[3] = fmaf(s, ca.w, q[3]);
        q[4] = fmaf(s, cb.x, q[4]); q[5] = fmaf(s, cb.y, q[5]);
        q[6] = fmaf(s, cb.z, q[6]); q[7] = fmaf(s, cb.w, q[7]);
    }
    float4* qdst = reinterpret_cast<float4*>(Q + (size_t)r * ZDIM);
    qdst[lane * 2]     = make_float4(q[0], q[1], q[2], q[3]);
    qdst[lane * 2 + 1] = make_float4(q[4], q[5], q[6], q[7]);
}

// ---------------------------------------------------------------------------
// K3: At = (Q @ r1)^T  and  Bt = Q @ r2^T   (masks applied at load; r1/r2
// never materialized). 64x64 output tiles, 4x4 per thread, BK=16.
//   r1[k][c]  = (k<=c) ? Rs[k][c] : 0
//   r2[c][k]  = (k> c) ? Rs[c][k] : (k==c ? r2diag[c] : 0)
// ---------------------------------------------------------------------------
__global__ void __launch_bounds__(256) small_gemm_kernel(const float* __restrict__ Q,
                                                         const float* __restrict__ Rs,
                                                         const float* __restrict__ r2diag,
                                                         float* __restrict__ At,
                                                         float* __restrict__ Bt) {
    int r0 = blockIdx.y * 64;
    int c0 = blockIdx.x * 64;
    int tid = threadIdx.x;
    int tx = tid & 15, ty = tid >> 4;

    __shared__ float Qs[16][68];
    __shared__ float RA[16][68];
    __shared__ float RB[16][68];

    float accA[4][4] = {};
    float accB[4][4] = {};

    for (int k0 = 0; k0 < ZDIM; k0 += 16) {
        {   // Q tile, transposed into [k][r]
            int r = tid >> 2, c4 = tid & 3;
            float4 g = *reinterpret_cast<const float4*>(Q + (size_t)(r0 + r) * ZDIM + k0 + c4 * 4);
            Qs[c4*4+0][r] = g.x; Qs[c4*4+1][r] = g.y; Qs[c4*4+2][r] = g.z; Qs[c4*4+3][r] = g.w;
        }
        {   // r1 tile (natural layout), upper-tri mask
            int kk = tid >> 4, c4 = tid & 15;
            int kg = k0 + kk, cg = c0 + c4 * 4;
            float4 g = *reinterpret_cast<const float4*>(Rs + (size_t)kg * MDIM + cg);
            float4 m;
            m.x = (kg <= cg + 0) ? g.x : 0.0f;
            m.y = (kg <= cg + 1) ? g.y : 0.0f;
            m.z = (kg <= cg + 2) ? g.z : 0.0f;
            m.w = (kg <= cg + 3) ? g.w : 0.0f;
            *reinterpret_cast<float4*>(&RA[kk][c4 * 4]) = m;
        }
        {   // r2^T tile: read Rs row cg, scatter transposed with strict-upper mask + diag
            int c = tid >> 2, k4 = tid & 3;
            int cg = c0 + c;
            float4 g = *reinterpret_cast<const float4*>(Rs + (size_t)cg * MDIM + k0 + k4 * 4);
            float gv[4] = {g.x, g.y, g.z, g.w};
#pragma unroll
            for (int qq = 0; qq < 4; ++qq) {
                int kg = k0 + k4 * 4 + qq;
                float val = (kg > cg) ? gv[qq] : ((kg == cg) ? r2diag[cg] : 0.0f);
                RB[k4 * 4 + qq][c] = val;
            }
        }
        __syncthreads();
#pragma unroll
        for (int kk = 0; kk < 16; ++kk) {
            float4 aq = *reinterpret_cast<const float4*>(&Qs[kk][ty * 4]);
            float4 ra = *reinterpret_cast<const float4*>(&RA[kk][tx * 4]);
            float4 rb = *reinterpret_cast<const float4*>(&RB[kk][tx * 4]);
            float av[4]  = {aq.x, aq.y, aq.z, aq.w};
            float rav[4] = {ra.x, ra.y, ra.z, ra.w};
            float rbv[4] = {rb.x, rb.y, rb.z, rb.w};
#pragma unroll
            for (int i = 0; i < 4; ++i)
#pragma unroll
                for (int j = 0; j < 4; ++j) {
                    accA[i][j] = fmaf(av[i], rav[j], accA[i][j]);
                    accB[i][j] = fmaf(av[i], rbv[j], accB[i][j]);
                }
        }
        __syncthreads();
    }
#pragma unroll
    for (int i = 0; i < 4; ++i) {
        int rg = r0 + ty * 4 + i;
#pragma unroll
        for (int j = 0; j < 4; ++j) {
            int cg = c0 + tx * 4 + j;
            At[(size_t)cg * ZDIM + rg] = accA[i][j];   // At[m][zi] = A[zi][m]
        }
        float4 o = make_float4(accB[i][0], accB[i][1], accB[i][2], accB[i][3]);
        *reinterpret_cast<float4*>(Bt + (size_t)rg * MDIM + c0 + tx * 4) = o;
    }
}

// ---------------------------------------------------------------------------
// K4: hB = tanh(z @ Bt + c) -> d_out[0:B*M] (fp32), plus per-row ldj partials
// (computed here since tanh' is available). 128x128 tile, 8x8/thread, BK=16.
// ldj region must be zeroed before launch (atomicAdd accumulation).
// ---------------------------------------------------------------------------
__global__ void __launch_bounds__(256) gemm1_kernel(const float* __restrict__ z,
                                                    const float* __restrict__ Bt,
                                                    const float* __restrict__ cvec,
                                                    const float* __restrict__ rrii,
                                                    float* __restrict__ hB,
                                                    float* __restrict__ ldj) {
    int b0 = blockIdx.x * 128;
    int c0 = blockIdx.y * 128;
    int tid = threadIdx.x;
    int tx = tid & 15, ty = tid >> 4;

    __shared__ float Zs[16][132];
    __shared__ float Bs[16][132];
    __shared__ float ldjbuf[128][17];

    float acc[8][8] = {};

    for (int k0 = 0; k0 < ZDIM; k0 += 16) {
#pragma unroll
        for (int s = 0; s < 2; ++s) {   // z tile, transposed into [k][row]
            int slot = s * 256 + tid;
            int r = slot >> 2, c4 = slot & 3;
            float4 g = *reinterpret_cast<const float4*>(z + (size_t)(b0 + r) * ZDIM + k0 + c4 * 4);
            Zs[c4*4+0][r] = g.x; Zs[c4*4+1][r] = g.y; Zs[c4*4+2][r] = g.z; Zs[c4*4+3][r] = g.w;
        }
#pragma unroll
        for (int s = 0; s < 2; ++s) {   // Bt tile (natural layout)
            int slot = s * 256 + tid;
            int kk = slot >> 5, c4 = slot & 31;
            float4 g = *reinterpret_cast<const float4*>(Bt + (size_t)(k0 + kk) * MDIM + c0 + c4 * 4);
            *reinterpret_cast<float4*>(&Bs[kk][c4 * 4]) = g;
        }
        __syncthreads();
#pragma unroll
        for (int kk = 0; kk < 16; ++kk) {
            float a[8], b[8];
            float4 t0 = *reinterpret_cast<const float4*>(&Zs[kk][ty * 8]);
            float4 t1 = *reinterpret_cast<const float4*>(&Zs[kk][ty * 8 + 4]);
            float4 t2 = *reinterpret_cast<const float4*>(&Bs[kk][tx * 8]);
            float4 t3 = *reinterpret_cast<const float4*>(&Bs[kk][tx * 8 + 4]);
            a[0]=t0.x; a[1]=t0.y; a[2]=t0.z; a[3]=t0.w; a[4]=t1.x; a[5]=t1.y; a[6]=t1.z; a[7]=t1.w;
            b[0]=t2.x; b[1]=t2.y; b[2]=t2.z; b[3]=t2.w; b[4]=t3.x; b[5]=t3.y; b[6]=t3.z; b[7]=t3.w;
#pragma unroll
            for (int i = 0; i < 8; ++i)
#pragma unroll
                for (int j = 0; j < 8; ++j)
                    acc[i][j] = fmaf(a[i], b[j], acc[i][j]);
        }
        __syncthreads();
    }

    float cv[8], rr[8];
#pragma unroll
    for (int j = 0; j < 8; ++j) {
        cv[j] = cvec[c0 + tx * 8 + j];
        rr[j] = rrii[c0 + tx * 8 + j];
    }
#pragma unroll
    for (int i = 0; i < 8; ++i) {
        int r = b0 + ty * 8 + i;
        float h[8];
        float p = 0.0f;
#pragma unroll
        for (int j = 0; j < 8; ++j) {
            float t  = acc[i][j] + cv[j];
            float hh = tanhf(t);
            h[j] = hh;
            float der = 1.0f - hh * hh;
            p += logf(fabsf(fmaf(der, rr[j], 1.0f)));
        }
        *reinterpret_cast<float4*>(hB + (size_t)r * MDIM + c0 + tx * 8)     = make_float4(h[0],h[1],h[2],h[3]);
        *reinterpret_cast<float4*>(hB + (size_t)r * MDIM + c0 + tx * 8 + 4) = make_float4(h[4],h[5],h[6],h[7]);
        ldjbuf[ty * 8 + i][tx] = p;
    }
    __syncthreads();
    if (tid < 128) {
        float s = 0.0f;
#pragma unroll
        for (int t = 0; t < 16; ++t) s += ldjbuf[tid][t];
        atomicAdd(&ldj[b0 + tid], s);
    }
}

// ---------------------------------------------------------------------------
// K5: z_out = hB @ A^T + z, IN-PLACE over hB in d_out. BN=512 (full N per
// block) so each block exclusively owns its batch rows -> in-place is safe
// (all global hB reads precede the final barrier; writes come after).
// 64x512 tile, 512 threads, 8x8/thread, BK=16.
// ---------------------------------------------------------------------------
__global__ void __launch_bounds__(512) gemm2_kernel(const float* __restrict__ z,
                                                    const float* __restrict__ At,
                                                    float* __restrict__ out) {
    int b0 = blockIdx.x * 64;
    int tid = threadIdx.x;
    int tx = tid & 63;   // col group 0..63 (cols tx*8..tx*8+7)
    int ty = tid >> 6;   // row group 0..7  (rows ty*8..ty*8+7)

    __shared__ float Hs[16][68];
    __shared__ float Bs[16][516];

    float acc[8][8] = {};

    for (int k0 = 0; k0 < MDIM; k0 += 16) {
        if (tid < 256) {   // hB tile (from d_out), transposed into [k][row]
            int r = tid >> 2, c4 = tid & 3;
            float4 g = *reinterpret_cast<const float4*>(out + (size_t)(b0 + r) * MDIM + k0 + c4 * 4);
            Hs[c4*4+0][r] = g.x; Hs[c4*4+1][r] = g.y; Hs[c4*4+2][r] = g.z; Hs[c4*4+3][r] = g.w;
        }
#pragma unroll
        for (int s = 0; s < 4; ++s) {   // At tile: 16 x 512 (natural layout)
            int slot = s * 512 + tid;
            int kk = slot >> 7, c4 = slot & 127;
            float4 g = *reinterpret_cast<const float4*>(At + (size_t)(k0 + kk) * ZDIM + c4 * 4);
            *reinterpret_cast<float4*>(&Bs[kk][c4 * 4]) = g;
        }
        __syncthreads();
#pragma unroll
        for (int kk = 0; kk < 16; ++kk) {
            float a[8], b[8];
            float4 t0 = *reinterpret_cast<const float4*>(&Hs[kk][ty * 8]);
            float4 t1 = *reinterpret_cast<const float4*>(&Hs[kk][ty * 8 + 4]);
            float4 t2 = *reinterpret_cast<const float4*>(&Bs[kk][tx * 8]);
            float4 t3 = *reinterpret_cast<const float4*>(&Bs[kk][tx * 8 + 4]);
            a[0]=t0.x; a[1]=t0.y; a[2]=t0.z; a[3]=t0.w; a[4]=t1.x; a[5]=t1.y; a[6]=t1.z; a[7]=t1.w;
            b[0]=t2.x; b[1]=t2.y; b[2]=t2.z; b[3]=t2.w; b[4]=t3.x; b[5]=t3.y; b[6]=t3.z; b[7]=t3.w;
#pragma unroll
            for (int i = 0; i < 8; ++i)
#pragma unroll
                for (int j = 0; j < 8; ++j)
                    acc[i][j] = fmaf(a[i], b[j], acc[i][j]);
        }
        __syncthreads();
    }

#pragma unroll
    for (int i = 0; i < 8; ++i) {
        int r = b0 + ty * 8 + i;
        float4 z0 = *reinterpret_cast<const float4*>(z + (size_t)r * ZDIM + tx * 8);
        float4 z1 = *reinterpret_cast<const float4*>(z + (size_t)r * ZDIM + tx * 8 + 4);
        float4 o0 = make_float4(acc[i][0] + z0.x, acc[i][1] + z0.y, acc[i][2] + z0.z, acc[i][3] + z0.w);
        float4 o1 = make_float4(acc[i][4] + z1.x, acc[i][5] + z1.y, acc[i][6] + z1.z, acc[i][7] + z1.w);
        *reinterpret_cast<float4*>(out + (size_t)r * ZDIM + tx * 8)     = o0;
        *reinterpret_cast<float4*>(out + (size_t)r * ZDIM + tx * 8 + 4) = o1;
    }
}

// ---------------------------------------------------------------------------
extern "C" void kernel_launch(void* const* d_in, const int* in_sizes, int n_in,
                              void* d_out, int out_size, void* d_ws, size_t ws_size,
                              hipStream_t stream) {
    const float* z      = (const float*)d_in[0];
    const float* v      = (const float*)d_in[1];
    const float* Rs     = (const float*)d_in[2];
    const float* r2diag = (const float*)d_in[3];
    const float* cvec   = (const float*)d_in[4];

    float* out = (float*)d_out;
    float* ldj = out + (size_t)NBATCH * ZDIM;   // d_out tail: 65536 floats

    float* ws   = (float*)d_ws;                 // ~4.2 MB of scratch
    float* vn   = ws;                           // 511*512
    float* Q    = ws + 1 * 262144;              // 512*512
    float* At   = ws + 2 * 262144;              // 512*512 (= A^T)
    float* Bt   = ws + 3 * 262144;              // 512*512
    float* rrii = ws + 4 * 262144;              // 512

    hipMemsetAsync(ldj, 0, NBATCH * sizeof(float), stream);  // atomicAdd target

    prep_kernel<<<512, 64, 0, stream>>>(v, Rs, r2diag, vn, rrii);
    householder_kernel<<<128, 256, 0, stream>>>(vn, Q);
    small_gemm_kernel<<<dim3(8, 8), 256, 0, stream>>>(Q, Rs, r2diag, At, Bt);
    gemm1_kernel<<<dim3(512, 4), 256, 0, stream>>>(z, Bt, cvec, rrii, out, ldj);
    gemm2_kernel<<<1024, 512, 0, stream>>>(z, At, out);
}

// Round 3
// 718.862 us; speedup vs baseline: 1.7170x; 1.7170x over previous
//
#include <hip/hip_runtime.h>
#include <math.h>
#include <stdint.h>

#define ZDIM   512
#define MDIM   512
#define HHN    511
#define NBATCH 65536

typedef float f32x4 __attribute__((ext_vector_type(4)));
typedef short s16x8 __attribute__((ext_vector_type(8)));

// float -> bf16 (round-to-nearest-even), returns low 16 bits
__device__ __forceinline__ uint32_t bf16rne(float x) {
    uint32_t u = __float_as_uint(x);
    return (u + 0x7fffu + ((u >> 16) & 1u)) >> 16;
}
// split x into hi+lo bf16 (x ~= hi + lo, |err| <~ 2^-18 |x|)
__device__ __forceinline__ void split2(float x, short& h, short& l) {
    uint32_t hu = bf16rne(x);
    float hf = __uint_as_float(hu << 16);
    uint32_t lu = bf16rne(x - hf);
    h = (short)hu; l = (short)lu;
}

// ---------------------------------------------------------------------------
// K1: normalize v rows -> vn ; rrii[m] = Rs[m,m] * r2diag[m]
// ---------------------------------------------------------------------------
__global__ void __launch_bounds__(64) prep_kernel(const float* __restrict__ v,
                                                  const float* __restrict__ Rs,
                                                  const float* __restrict__ r2diag,
                                                  float* __restrict__ vn,
                                                  float* __restrict__ rrii) {
    int b    = blockIdx.x;
    int lane = threadIdx.x;  // 64
    if (b < HHN) {
        const float4* src = reinterpret_cast<const float4*>(v + (size_t)b * ZDIM);
        float4 a0 = src[lane * 2];
        float4 a1 = src[lane * 2 + 1];
        float s = a0.x*a0.x + a0.y*a0.y + a0.z*a0.z + a0.w*a0.w
                + a1.x*a1.x + a1.y*a1.y + a1.z*a1.z + a1.w*a1.w;
#pragma unroll
        for (int off = 32; off >= 1; off >>= 1) s += __shfl_xor(s, off, 64);
        float inv = 1.0f / sqrtf(s);
        float4 o0 = make_float4(a0.x*inv, a0.y*inv, a0.z*inv, a0.w*inv);
        float4 o1 = make_float4(a1.x*inv, a1.y*inv, a1.z*inv, a1.w*inv);
        float4* dst = reinterpret_cast<float4*>(vn + (size_t)b * ZDIM);
        dst[lane * 2]     = o0;
        dst[lane * 2 + 1] = o1;
    } else {
        for (int m = lane; m < MDIM; m += 64)
            rrii[m] = Rs[(size_t)m * MDIM + m] * r2diag[m];
    }
}

// ---------------------------------------------------------------------------
// K2: Householder product, row-parallel (one wave per row of Q). fp32.
// ---------------------------------------------------------------------------
__global__ void __launch_bounds__(256) householder_kernel(const float* __restrict__ vn,
                                                          float* __restrict__ Q) {
    int wave = threadIdx.x >> 6;
    int lane = threadIdx.x & 63;
    int r    = blockIdx.x * 4 + wave;

    float q[8];
#pragma unroll
    for (int j = 0; j < 8; ++j) q[j] = 0.0f;
    int base = r - lane * 8;
    if (base >= 0 && base < 8) q[base] = 1.0f;

    const float4* vn4 = reinterpret_cast<const float4*>(vn);
    float4 va = vn4[lane * 2];
    float4 vb = vn4[lane * 2 + 1];
    for (int i = 0; i < HHN; ++i) {
        float4 ca = va, cb = vb;
        if (i + 1 < HHN) {
            va = vn4[(size_t)(i + 1) * (ZDIM / 4) + lane * 2];
            vb = vn4[(size_t)(i + 1) * (ZDIM / 4) + lane * 2 + 1];
        }
        float d = q[0]*ca.x + q[1]*ca.y + q[2]*ca.z + q[3]*ca.w
                + q[4]*cb.x + q[5]*cb.y + q[6]*cb.z + q[7]*cb.w;
#pragma unroll
        for (int off = 32; off >= 1; off >>= 1) d += __shfl_xor(d, off, 64);
        float s = -2.0f * d;
        q[0] = fmaf(s, ca.x, q[0]); q[1] = fmaf(s, ca.y, q[1]);
        q[2] = fmaf(s, ca.z, q[2]); q[3] = fmaf(s, ca.w, q[3]);
        q[4] = fmaf(s, cb.x, q[4]); q[5] = fmaf(s, cb.y, q[5]);
        q[6] = fmaf(s, cb.z, q[6]); q[7] = fmaf(s, cb.w, q[7]);
    }
    float4* qdst = reinterpret_cast<float4*>(Q + (size_t)r * ZDIM);
    qdst[lane * 2]     = make_float4(q[0], q[1], q[2], q[3]);
    qdst[lane * 2 + 1] = make_float4(q[4], q[5], q[6], q[7]);
}

// ---------------------------------------------------------------------------
// K3: A = Q @ r1 (natural [z][m], k=m contiguous for gemm2 B-operand) and
//     B1 = (Q @ r2^T)^T (layout [m][z], k=z contiguous for gemm1 B-operand).
// Both emitted as SPLIT bf16 hi/lo short arrays. fp32 accumulate inside.
// ---------------------------------------------------------------------------
__global__ void __launch_bounds__(256) small_gemm_kernel(const float* __restrict__ Q,
                                                         const float* __restrict__ Rs,
                                                         const float* __restrict__ r2diag,
                                                         short* __restrict__ Ah_g,
                                                         short* __restrict__ Al_g,
                                                         short* __restrict__ B1h_g,
                                                         short* __restrict__ B1l_g) {
    int r0 = blockIdx.y * 64;
    int c0 = blockIdx.x * 64;
    int tid = threadIdx.x;
    int tx = tid & 15, ty = tid >> 4;

    __shared__ float Qs[16][68];
    __shared__ float RA[16][68];
    __shared__ float RB[16][68];

    float accA[4][4] = {};
    float accB[4][4] = {};

    for (int k0 = 0; k0 < ZDIM; k0 += 16) {
        {   // Q tile, transposed into [k][r]
            int r = tid >> 2, c4 = tid & 3;
            float4 g = *reinterpret_cast<const float4*>(Q + (size_t)(r0 + r) * ZDIM + k0 + c4 * 4);
            Qs[c4*4+0][r] = g.x; Qs[c4*4+1][r] = g.y; Qs[c4*4+2][r] = g.z; Qs[c4*4+3][r] = g.w;
        }
        {   // r1 tile (upper-tri mask)
            int kk = tid >> 4, c4 = tid & 15;
            int kg = k0 + kk, cg = c0 + c4 * 4;
            float4 g = *reinterpret_cast<const float4*>(Rs + (size_t)kg * MDIM + cg);
            float4 m;
            m.x = (kg <= cg + 0) ? g.x : 0.0f;
            m.y = (kg <= cg + 1) ? g.y : 0.0f;
            m.z = (kg <= cg + 2) ? g.z : 0.0f;
            m.w = (kg <= cg + 3) ? g.w : 0.0f;
            *reinterpret_cast<float4*>(&RA[kk][c4 * 4]) = m;
        }
        {   // r2^T tile (strict upper + diag, transposed scatter)
            int c = tid >> 2, k4 = tid & 3;
            int cg = c0 + c;
            float4 g = *reinterpret_cast<const float4*>(Rs + (size_t)cg * MDIM + k0 + k4 * 4);
            float gv[4] = {g.x, g.y, g.z, g.w};
#pragma unroll
            for (int qq = 0; qq < 4; ++qq) {
                int kg = k0 + k4 * 4 + qq;
                float val = (kg > cg) ? gv[qq] : ((kg == cg) ? r2diag[cg] : 0.0f);
                RB[k4 * 4 + qq][c] = val;
            }
        }
        __syncthreads();
#pragma unroll
        for (int kk = 0; kk < 16; ++kk) {
            float4 aq = *reinterpret_cast<const float4*>(&Qs[kk][ty * 4]);
            float4 ra = *reinterpret_cast<const float4*>(&RA[kk][tx * 4]);
            float4 rb = *reinterpret_cast<const float4*>(&RB[kk][tx * 4]);
            float av[4]  = {aq.x, aq.y, aq.z, aq.w};
            float rav[4] = {ra.x, ra.y, ra.z, ra.w};
            float rbv[4] = {rb.x, rb.y, rb.z, rb.w};
#pragma unroll
            for (int i = 0; i < 4; ++i)
#pragma unroll
                for (int j = 0; j < 4; ++j) {
                    accA[i][j] = fmaf(av[i], rav[j], accA[i][j]);
                    accB[i][j] = fmaf(av[i], rbv[j], accB[i][j]);
                }
        }
        __syncthreads();
    }
#pragma unroll
    for (int i = 0; i < 4; ++i) {
        int rg = r0 + ty * 4 + i;  // z index
#pragma unroll
        for (int j = 0; j < 4; ++j) {
            int cg = c0 + tx * 4 + j;  // m index
            short h, l;
            split2(accA[i][j], h, l);               // A natural [z][m]
            Ah_g[(size_t)rg * MDIM + cg] = h;
            Al_g[(size_t)rg * MDIM + cg] = l;
            split2(accB[i][j], h, l);               // B1 = Bt^T : [m][z]
            B1h_g[(size_t)cg * ZDIM + rg] = h;
            B1l_g[(size_t)cg * ZDIM + rg] = l;
        }
    }
}

// ---------------------------------------------------------------------------
// K4: gemm1 MFMA split-3: Btzc = z @ Bt + c; hB = tanh -> packed (hi|lo<<16)
// u32 into d_out; ldj partials fused. Tile 128x256, 4 waves (wave 64x128),
// mfma_f32_16x16x32_bf16, BK=32. z converted fp32->hi/lo during staging.
// ---------------------------------------------------------------------------
__global__ void __launch_bounds__(256, 2) gemm1_mfma(const float* __restrict__ z,
                                                     const short* __restrict__ B1h,
                                                     const short* __restrict__ B1l,
                                                     const float* __restrict__ cvec,
                                                     const float* __restrict__ rrii,
                                                     uint32_t* __restrict__ hBp,
                                                     float* __restrict__ ldj) {
    int b0 = blockIdx.x * 128;
    int c0 = blockIdx.y * 256;
    int tid = threadIdx.x;

    __shared__ short Azh[128][40], Azl[128][40];
    __shared__ short Bsh[256][40], Bsl[256][40];

    int wid = tid >> 6, lane = tid & 63;
    int wm = wid >> 1, wn = wid & 1;          // wave grid 2x2
    int lrow = lane & 15, lk = (lane >> 4) * 8;

    f32x4 acc[4][8];
#pragma unroll
    for (int m = 0; m < 4; ++m)
#pragma unroll
        for (int n = 0; n < 8; ++n) acc[m][n] = (f32x4){0.f, 0.f, 0.f, 0.f};

    for (int k0 = 0; k0 < ZDIM; k0 += 32) {
        {   // stage z tile [128][32] -> hi/lo bf16
            int r = tid >> 1, half = tid & 1;
            const float* zp = z + (size_t)(b0 + r) * ZDIM + k0 + half * 16;
            float xv[16];
            *reinterpret_cast<float4*>(&xv[0])  = *reinterpret_cast<const float4*>(zp);
            *reinterpret_cast<float4*>(&xv[4])  = *reinterpret_cast<const float4*>(zp + 4);
            *reinterpret_cast<float4*>(&xv[8])  = *reinterpret_cast<const float4*>(zp + 8);
            *reinterpret_cast<float4*>(&xv[12]) = *reinterpret_cast<const float4*>(zp + 12);
            s16x8 h0, h1, l0, l1;
#pragma unroll
            for (int j = 0; j < 8; ++j) { short hh, ll; split2(xv[j],     hh, ll); h0[j] = hh; l0[j] = ll; }
#pragma unroll
            for (int j = 0; j < 8; ++j) { short hh, ll; split2(xv[8 + j], hh, ll); h1[j] = hh; l1[j] = ll; }
            *reinterpret_cast<s16x8*>(&Azh[r][half * 16])     = h0;
            *reinterpret_cast<s16x8*>(&Azh[r][half * 16 + 8]) = h1;
            *reinterpret_cast<s16x8*>(&Azl[r][half * 16])     = l0;
            *reinterpret_cast<s16x8*>(&Azl[r][half * 16 + 8]) = l1;
        }
        {   // stage B1 tile [256][32] (already split bf16)
            const short* ph = B1h + (size_t)(c0 + tid) * ZDIM + k0;
            const short* pl = B1l + (size_t)(c0 + tid) * ZDIM + k0;
#pragma unroll
            for (int s = 0; s < 4; ++s)
                *reinterpret_cast<s16x8*>(&Bsh[tid][s * 8]) = *reinterpret_cast<const s16x8*>(ph + s * 8);
#pragma unroll
            for (int s = 0; s < 4; ++s)
                *reinterpret_cast<s16x8*>(&Bsl[tid][s * 8]) = *reinterpret_cast<const s16x8*>(pl + s * 8);
        }
        __syncthreads();

        s16x8 ah[4], al[4];
#pragma unroll
        for (int m = 0; m < 4; ++m) {
            ah[m] = *reinterpret_cast<const s16x8*>(&Azh[wm * 64 + m * 16 + lrow][lk]);
            al[m] = *reinterpret_cast<const s16x8*>(&Azl[wm * 64 + m * 16 + lrow][lk]);
        }
#pragma unroll
        for (int n = 0; n < 8; ++n) {
            s16x8 bh = *reinterpret_cast<const s16x8*>(&Bsh[wn * 128 + n * 16 + lrow][lk]);
            s16x8 bl = *reinterpret_cast<const s16x8*>(&Bsl[wn * 128 + n * 16 + lrow][lk]);
#pragma unroll
            for (int m = 0; m < 4; ++m) {
                acc[m][n] = __builtin_amdgcn_mfma_f32_16x16x32_bf16(ah[m], bh, acc[m][n], 0, 0, 0);
                acc[m][n] = __builtin_amdgcn_mfma_f32_16x16x32_bf16(al[m], bh, acc[m][n], 0, 0, 0);
                acc[m][n] = __builtin_amdgcn_mfma_f32_16x16x32_bf16(ah[m], bl, acc[m][n], 0, 0, 0);
            }
        }
        __syncthreads();
    }

    // epilogue: tanh, pack hB, ldj partials
    float cv[8], rr[8];
#pragma unroll
    for (int n = 0; n < 8; ++n) {
        int col = c0 + wn * 128 + n * 16 + lrow;
        cv[n] = cvec[col];
        rr[n] = rrii[col];
    }
    float lsum[4][4];
#pragma unroll
    for (int m = 0; m < 4; ++m)
#pragma unroll
        for (int r = 0; r < 4; ++r) lsum[m][r] = 0.0f;

#pragma unroll
    for (int m = 0; m < 4; ++m) {
#pragma unroll
        for (int r = 0; r < 4; ++r) {
            int b = b0 + wm * 64 + m * 16 + (lane >> 4) * 4 + r;
#pragma unroll
            for (int n = 0; n < 8; ++n) {
                float val = acc[m][n][r] + cv[n];
                float h = tanhf(val);
                short hh, ll;
                split2(h, hh, ll);
                int col = c0 + wn * 128 + n * 16 + lrow;
                hBp[(size_t)b * MDIM + col] = (uint32_t)(uint16_t)hh | ((uint32_t)(uint16_t)ll << 16);
                float der = 1.0f - h * h;
                lsum[m][r] += logf(fabsf(fmaf(der, rr[n], 1.0f)));
            }
        }
    }
#pragma unroll
    for (int m = 0; m < 4; ++m) {
#pragma unroll
        for (int r = 0; r < 4; ++r) {
            float s = lsum[m][r];
            s += __shfl_xor(s, 1, 64);
            s += __shfl_xor(s, 2, 64);
            s += __shfl_xor(s, 4, 64);
            s += __shfl_xor(s, 8, 64);
            if ((lane & 15) == 0)
                atomicAdd(&ldj[b0 + wm * 64 + m * 16 + (lane >> 4) * 4 + r], s);
        }
    }
}

// ---------------------------------------------------------------------------
// K5: gemm2 MFMA split-3, IN-PLACE: z_out = hB @ A^T + z over packed hB in
// d_out. Tile 128x512 (full N -> block owns its rows, in-place safe),
// 8 waves (wave 64x128), BK=32. hB unpacked from (hi|lo<<16) during staging.
// ---------------------------------------------------------------------------
__global__ void __launch_bounds__(512, 2) gemm2_mfma(const float* __restrict__ z,
                                                     const short* __restrict__ Ah_g,
                                                     const short* __restrict__ Al_g,
                                                     float* __restrict__ out) {
    int b0 = blockIdx.x * 128;
    int tid = threadIdx.x;
    const uint32_t* hBp = reinterpret_cast<const uint32_t*>(out);

    __shared__ short Hh[128][40], Hl[128][40];
    __shared__ short Ash[512][40], Asl[512][40];

    int wid = tid >> 6, lane = tid & 63;
    int wm = wid >> 2, wn = wid & 3;          // wave grid 2x4
    int lrow = lane & 15, lk = (lane >> 4) * 8;

    f32x4 acc[4][8];
#pragma unroll
    for (int m = 0; m < 4; ++m)
#pragma unroll
        for (int n = 0; n < 8; ++n) acc[m][n] = (f32x4){0.f, 0.f, 0.f, 0.f};

    for (int m0 = 0; m0 < MDIM; m0 += 32) {
        {   // stage hB tile [128][32] u32 -> unpack hi/lo
            int r = tid >> 2, q = tid & 3;
            const uint32_t* hp = hBp + (size_t)(b0 + r) * MDIM + m0 + q * 8;
            uint4 u0 = *reinterpret_cast<const uint4*>(hp);
            uint4 u1 = *reinterpret_cast<const uint4*>(hp + 4);
            uint32_t uv[8] = {u0.x, u0.y, u0.z, u0.w, u1.x, u1.y, u1.z, u1.w};
            s16x8 vh, vl;
#pragma unroll
            for (int j = 0; j < 8; ++j) {
                vh[j] = (short)(uv[j] & 0xffffu);
                vl[j] = (short)(uv[j] >> 16);
            }
            *reinterpret_cast<s16x8*>(&Hh[r][q * 8]) = vh;
            *reinterpret_cast<s16x8*>(&Hl[r][q * 8]) = vl;
        }
        {   // stage A tile [512][32] (all n rows), already split bf16
            const short* ph = Ah_g + (size_t)tid * MDIM + m0;
            const short* pl = Al_g + (size_t)tid * MDIM + m0;
#pragma unroll
            for (int s = 0; s < 4; ++s)
                *reinterpret_cast<s16x8*>(&Ash[tid][s * 8]) = *reinterpret_cast<const s16x8*>(ph + s * 8);
#pragma unroll
            for (int s = 0; s < 4; ++s)
                *reinterpret_cast<s16x8*>(&Asl[tid][s * 8]) = *reinterpret_cast<const s16x8*>(pl + s * 8);
        }
        __syncthreads();

        s16x8 ah[4], al[4];
#pragma unroll
        for (int m = 0; m < 4; ++m) {
            ah[m] = *reinterpret_cast<const s16x8*>(&Hh[wm * 64 + m * 16 + lrow][lk]);
            al[m] = *reinterpret_cast<const s16x8*>(&Hl[wm * 64 + m * 16 + lrow][lk]);
        }
#pragma unroll
        for (int n = 0; n < 8; ++n) {
            s16x8 bh = *reinterpret_cast<const s16x8*>(&Ash[wn * 128 + n * 16 + lrow][lk]);
            s16x8 bl = *reinterpret_cast<const s16x8*>(&Asl[wn * 128 + n * 16 + lrow][lk]);
#pragma unroll
            for (int m = 0; m < 4; ++m) {
                acc[m][n] = __builtin_amdgcn_mfma_f32_16x16x32_bf16(ah[m], bh, acc[m][n], 0, 0, 0);
                acc[m][n] = __builtin_amdgcn_mfma_f32_16x16x32_bf16(al[m], bh, acc[m][n], 0, 0, 0);
                acc[m][n] = __builtin_amdgcn_mfma_f32_16x16x32_bf16(ah[m], bl, acc[m][n], 0, 0, 0);
            }
        }
        __syncthreads();
    }

    // epilogue: += z, write fp32 (overwrites packed hB; block owns these rows)
#pragma unroll
    for (int m = 0; m < 4; ++m) {
#pragma unroll
        for (int r = 0; r < 4; ++r) {
            int b = b0 + wm * 64 + m * 16 + (lane >> 4) * 4 + r;
#pragma unroll
            for (int n = 0; n < 8; ++n) {
                int colz = wn * 128 + n * 16 + lrow;
                out[(size_t)b * ZDIM + colz] = acc[m][n][r] + z[(size_t)b * ZDIM + colz];
            }
        }
    }
}

// ---------------------------------------------------------------------------
extern "C" void kernel_launch(void* const* d_in, const int* in_sizes, int n_in,
                              void* d_out, int out_size, void* d_ws, size_t ws_size,
                              hipStream_t stream) {
    const float* z      = (const float*)d_in[0];
    const float* v      = (const float*)d_in[1];
    const float* Rs     = (const float*)d_in[2];
    const float* r2diag = (const float*)d_in[3];
    const float* cvec   = (const float*)d_in[4];

    float* out = (float*)d_out;
    float* ldj = out + (size_t)NBATCH * ZDIM;

    // ws layout: floats then shorts (all 16B-aligned)
    float* ws   = (float*)d_ws;
    float* vn   = ws;                     // 511*512 f32 (use 262144 slot)
    float* Q    = ws + 262144;            // 512*512 f32
    float* rrii = ws + 524288;            // 512 f32
    short* sbase = (short*)(ws + 524800);
    short* Ah_g = sbase;                  // 512*512 bf16-hi of A (natural [z][m])
    short* Al_g = sbase + 262144;
    short* B1h  = sbase + 2 * 262144;     // 512*512 bf16-hi of B1 = Bt^T ([m][z])
    short* B1l  = sbase + 3 * 262144;

    hipMemsetAsync(ldj, 0, NBATCH * sizeof(float), stream);

    prep_kernel<<<512, 64, 0, stream>>>(v, Rs, r2diag, vn, rrii);
    householder_kernel<<<128, 256, 0, stream>>>(vn, Q);
    small_gemm_kernel<<<dim3(8, 8), 256, 0, stream>>>(Q, Rs, r2diag, Ah_g, Al_g, B1h, B1l);
    gemm1_mfma<<<dim3(512, 2), 256, 0, stream>>>(z, B1h, B1l, cvec, rrii,
                                                 (uint32_t*)out, ldj);
    gemm2_mfma<<<512, 512, 0, stream>>>(z, Ah_g, Al_g, out);
}